// Round 9
// baseline (803.766 us; speedup 1.0000x reference)
//
#include <hip/hip_runtime.h>
#include <stdint.h>

typedef unsigned short u16;
typedef unsigned int u32;
typedef __attribute__((ext_vector_type(8))) short short8;   // 8 bf16 (4 VGPR)
typedef __attribute__((ext_vector_type(4))) float f32x4;

#define NTHR 384
#define K2E16 0.09016844005556021f   /* log2(e)/16 : 1/sqrt(256) folded into exp2 */

// LDS map (43904 B total; target 2 blocks/CU):
//   wvoL  [0, 16384)     : Wvo 8KB chunks, double-buffered (P2b)
//   kwL   [16384, 42496) : KW bf16 [96][272B] (P1..P2); fragH 24576 (P5..P6)
//   biasL f32[96] @42496, bvoL f32[256] @42880
#define KW_OFF    16384
#define KW_STRIDE 272
#define BIAS_OFF  42496
#define BVO_OFF   42880
#define LDS_TOTAL 43904

static __device__ __forceinline__ u16 f2bf(float f) {
  union { float f; u32 u; } v; v.f = f;
  u32 r = v.u + 0x7FFFu + ((v.u >> 16) & 1u);   // RNE
  return (u16)(r >> 16);
}

// ---------------------------------------------------------------------------
// K0: weight prep.
//  - WkqE[de][c]: c<128 -> sum_h Wk[de][h]*Wq[c][h]; c==128 -> Wk[de]·bq;
//                 129..143 -> 0. bf16 MFMA B-frags (K=128, 9 col-tiles).
//    (bk-dependent score terms are constant over p -> cancel in softmax.)
//  - WvoF = bf16 B-frags of Wv@Wo, frag index (kt*16+nt): contiguous 1KB per
//    frag, so any (kt, nt-half) pair is a contiguous 8KB chunk.
//  - bvo = bv@Wo + bo (f32).
// ---------------------------------------------------------------------------
__global__ __launch_bounds__(256) void k_setup(
    const float* __restrict__ Wq, const float* __restrict__ Wk,
    const float* __restrict__ Wv, const float* __restrict__ Wo,
    const float* __restrict__ bq,
    const float* __restrict__ bv, const float* __restrict__ bo,
    u16* __restrict__ WkqF, u16* __restrict__ WvoF, float* __restrict__ bvo) {
  const int ci = blockIdx.x;   // k-row
  const int co = threadIdx.x;  // col
  float acc = 0.f;
  for (int h = 0; h < 256; ++h) acc += Wv[ci*256 + h] * Wo[h*256 + co];
  const int lanepart = ((ci >> 3) & 3)*16 + (co & 15), e = ci & 7;
  const int idxv = (((ci >> 5)*16 + (co >> 4))*64 + lanepart)*8 + e;
  WvoF[idxv] = f2bf(acc);
  if (ci < 128 && co < 144) {
    float a = 0.f;
    if (co < 128)       { for (int h = 0; h < 256; ++h) a += Wk[ci*256 + h] * Wq[co*256 + h]; }
    else if (co == 128) { for (int h = 0; h < 256; ++h) a += Wk[ci*256 + h] * bq[h]; }
    const int idx = (((ci >> 5)*9 + (co >> 4))*64 + lanepart)*8 + e;
    WkqF[idx] = f2bf(a);
  }
  if (ci == 0) {
    float a2 = 0.f;
    for (int h = 0; h < 256; ++h) a2 += bv[h] * Wo[h*256 + co];
    bvo[co] = a2 + bo[co];
  }
}

// ---------------------------------------------------------------------------
// K2 fused, grid (1024, 8), 6 waves, 43904B LDS (2 blocks/CU target).
// M-partition: wave w owns rows [16w,16w+16) of every per-(b,n) matrix.
//   P0: issue sd/se reg loads + Wvo chunk0 loads; biases
//   P1: KW = bf16(senc_rows)@WkqE -> kwL (B-frags direct global, L2-hot);
//       col128 -> biasL; chunk0 -> wvoL.buf0
//   P2: issue enc reg loads; scoresT = KW@sdecT + bias; softmax; af pack
//   P2b: 16x 8KB chunk ci=(kt,h): {prefetch ci+1; 8 MFMA buf[ci&1];
//        ds_write ci+1 -> buf[(ci+1)&1]; barrier}
//   P5/P6: sigma frags in two 24KB halves over kwL; PV; +bvo; f32 stores
// ---------------------------------------------------------------------------
__global__ __launch_bounds__(NTHR, 3) void k_attn(
    const float* __restrict__ sdec, const float* __restrict__ senc,
    const float* __restrict__ enc,
    const u16* __restrict__ WkqF, const u16* __restrict__ WvoF,
    const float* __restrict__ bvo, float* __restrict__ out) {
  extern __shared__ char smem[];
  char* wvoL   = smem;
  char* kwL    = smem + KW_OFF;
  char* fragH  = smem + KW_OFF;    // 24576 over kwL (P5..P6)
  float* biasL = (float*)(smem + BIAS_OFF);
  float* bvoL  = (float*)(smem + BVO_OFF);

  const int n = blockIdx.x, b = blockIdx.y;
  const int tid = threadIdx.x, wave = tid >> 6, lane = tid & 63;
  const int g = lane >> 4, c15 = lane & 15;
  const int prow = 16*wave + c15;      // this wave's A-fragment row

  // ---- P0: issue sdec/senc reg loads + Wvo chunk0 (8KB) loads ----
  const float* sdp = sdec + ((size_t)((b*96 + prow)*1024 + n))*128 + 8*g;
  const float* sep = senc + ((size_t)((b*96 + prow)*1024 + n))*128 + 8*g;
  float4 sdv[4][2], sev[4][2];
  #pragma unroll
  for (int kt = 0; kt < 4; ++kt) {
    sev[kt][0] = *(const float4*)(sep + 32*kt);
    sev[kt][1] = *(const float4*)(sep + 32*kt + 4);
    sdv[kt][0] = *(const float4*)(sdp + 32*kt);
    sdv[kt][1] = *(const float4*)(sdp + 32*kt + 4);
  }
  const f32x4* wv = (const f32x4*)WvoF;   // chunk ci = wv + ci*512 (8KB)
  f32x4 c0a, c0b;
  c0a = wv[tid];
  if (tid < 128) c0b = wv[384 + tid];
  if (tid < 256) bvoL[tid] = bvo[tid];

  short8 sef[4], sdf[4];
  #pragma unroll
  for (int kt = 0; kt < 4; ++kt) {
    union { u32 u[4]; short8 v; } cv;
    cv.u[0] = (u32)f2bf(sev[kt][0].x) | ((u32)f2bf(sev[kt][0].y) << 16);
    cv.u[1] = (u32)f2bf(sev[kt][0].z) | ((u32)f2bf(sev[kt][0].w) << 16);
    cv.u[2] = (u32)f2bf(sev[kt][1].x) | ((u32)f2bf(sev[kt][1].y) << 16);
    cv.u[3] = (u32)f2bf(sev[kt][1].z) | ((u32)f2bf(sev[kt][1].w) << 16);
    sef[kt] = cv.v;
  }
  #pragma unroll
  for (int kt = 0; kt < 4; ++kt) {
    union { u32 u[4]; short8 v; } cv;
    cv.u[0] = (u32)f2bf(sdv[kt][0].x) | ((u32)f2bf(sdv[kt][0].y) << 16);
    cv.u[1] = (u32)f2bf(sdv[kt][0].z) | ((u32)f2bf(sdv[kt][0].w) << 16);
    cv.u[2] = (u32)f2bf(sdv[kt][1].x) | ((u32)f2bf(sdv[kt][1].y) << 16);
    cv.u[3] = (u32)f2bf(sdv[kt][1].z) | ((u32)f2bf(sdv[kt][1].w) << 16);
    sdf[kt] = cv.v;
  }

  // ---- P1: KW rows [16w,16w+16) x 144 = senc_rows @ WkqE (B direct global) ----
  {
    f32x4 acc[9];
    #pragma unroll
    for (int nt = 0; nt < 9; ++nt) acc[nt] = (f32x4)0.f;
    #pragma unroll
    for (int kt = 0; kt < 4; ++kt) {
      #pragma unroll
      for (int nt = 0; nt < 9; ++nt) {
        const short8 bf = *(const short8*)(WkqF + (size_t)((kt*9 + nt)*64 + lane)*8);
        acc[nt] = __builtin_amdgcn_mfma_f32_16x16x32_bf16(sef[kt], bf, acc[nt], 0, 0, 0);
      }
    }
    #pragma unroll
    for (int nt = 0; nt < 8; ++nt) {
      #pragma unroll
      for (int r = 0; r < 4; ++r)
        *(u16*)(kwL + (16*wave + 4*g + r)*KW_STRIDE + 2*(c15 + 16*nt)) = f2bf(acc[nt][r]);
    }
    if (c15 == 0) {
      #pragma unroll
      for (int r = 0; r < 4; ++r) biasL[16*wave + 4*g + r] = acc[8][r];
    }
  }
  // commit Wvo chunk0 -> buf0
  {
    f32x4* b0 = (f32x4*)wvoL;
    b0[tid] = c0a;
    if (tid < 128) b0[384 + tid] = c0b;
  }
  __syncthreads();   // bar1: kwL + biasL + chunk0 ready

  // ---- issue enc reg loads (consumed per-kt in P2b; fly during P2) ----
  const float* ep = enc + ((size_t)((b*96 + prow)*1024 + n))*256 + 8*g;
  float4 ev[8][2];
  #pragma unroll
  for (int kt = 0; kt < 8; ++kt) {
    ev[kt][0] = *(const float4*)(ep + 32*kt);
    ev[kt][1] = *(const float4*)(ep + 32*kt + 4);
  }

  // ---- P2: scoresT = KW[:,0:128] @ sdecT + bias; softmax; af pack ----
  f32x4 sac[6];
  #pragma unroll
  for (int pt = 0; pt < 6; ++pt) sac[pt] = (f32x4)0.f;
  #pragma unroll
  for (int kt = 0; kt < 4; ++kt) {
    #pragma unroll
    for (int pt = 0; pt < 6; ++pt) {
      const short8 kf = *(const short8*)(kwL + (16*pt + c15)*KW_STRIDE + 16*g + 64*kt);
      sac[pt] = __builtin_amdgcn_mfma_f32_16x16x32_bf16(kf, sdf[kt], sac[pt], 0, 0, 0);
    }
  }
  #pragma unroll
  for (int pt = 0; pt < 6; ++pt)
    #pragma unroll
    for (int r = 0; r < 4; ++r)
      sac[pt][r] += biasL[16*pt + 4*g + r];

  float m = sac[0][0];
  #pragma unroll
  for (int pt = 0; pt < 6; ++pt)
    #pragma unroll
    for (int r = 0; r < 4; ++r) m = fmaxf(m, sac[pt][r]);
  m = fmaxf(m, __shfl_xor(m, 16));
  m = fmaxf(m, __shfl_xor(m, 32));
  float s = 0.f;
  #pragma unroll
  for (int pt = 0; pt < 6; ++pt)
    #pragma unroll
    for (int r = 0; r < 4; ++r) {
      const float e = exp2f((sac[pt][r] - m) * K2E16);
      sac[pt][r] = e; s += e;
    }
  s += __shfl_xor(s, 16);
  s += __shfl_xor(s, 32);
  const float rs = 1.f / s;

  short8 af[3];
  #pragma unroll
  for (int kb = 0; kb < 3; ++kb) {
    union { u32 u[4]; short8 v; } cv;
    cv.u[0] = (u32)f2bf(sac[2*kb][0]*rs)   | ((u32)f2bf(sac[2*kb][1]*rs)   << 16);
    cv.u[1] = (u32)f2bf(sac[2*kb][2]*rs)   | ((u32)f2bf(sac[2*kb][3]*rs)   << 16);
    cv.u[2] = (u32)f2bf(sac[2*kb+1][0]*rs) | ((u32)f2bf(sac[2*kb+1][1]*rs) << 16);
    cv.u[3] = (u32)f2bf(sac[2*kb+1][2]*rs) | ((u32)f2bf(sac[2*kb+1][3]*rs) << 16);
    af[kb] = cv.v;
  }

  // ---- P2b: enc2 = enc_rows @ Wvo; 16 x 8KB chunks, double-buffered ----
  // chunk ci = kt*2 + h: frags (kt*16 + 8h + ntl), ntl 0..7 -> acc2[8h+ntl]
  f32x4 acc2[16];
  #pragma unroll
  for (int nt = 0; nt < 16; ++nt) acc2[nt] = (f32x4)0.f;
  short8 acur;
  #pragma unroll
  for (int ci = 0; ci < 16; ++ci) {
    // prefetch next chunk to regs (flies under this chunk's MFMAs)
    f32x4 nxa, nxb;
    if (ci < 15) {
      const f32x4* src = wv + (ci + 1)*512;
      nxa = src[tid];
      if (tid < 128) nxb = src[384 + tid];
    }
    if ((ci & 1) == 0) {
      const int kt = ci >> 1;
      union { u32 u[4]; short8 v; } cv;
      cv.u[0] = (u32)f2bf(ev[kt][0].x) | ((u32)f2bf(ev[kt][0].y) << 16);
      cv.u[1] = (u32)f2bf(ev[kt][0].z) | ((u32)f2bf(ev[kt][0].w) << 16);
      cv.u[2] = (u32)f2bf(ev[kt][1].x) | ((u32)f2bf(ev[kt][1].y) << 16);
      cv.u[3] = (u32)f2bf(ev[kt][1].z) | ((u32)f2bf(ev[kt][1].w) << 16);
      acur = cv.v;
    }
    const char* buf = wvoL + (ci & 1)*8192;
    const int ntb = (ci & 1)*8;
    #pragma unroll
    for (int ntl = 0; ntl < 8; ++ntl) {
      const short8 bf = *(const short8*)(buf + ((ntl*64 + lane) << 4));
      acc2[ntb + ntl] = __builtin_amdgcn_mfma_f32_16x16x32_bf16(acur, bf, acc2[ntb + ntl], 0, 0, 0);
    }
    if (ci < 15) {
      f32x4* bw = (f32x4*)(wvoL + ((ci + 1) & 1)*8192);
      bw[tid] = nxa;
      if (tid < 128) bw[384 + tid] = nxb;
    }
    __syncthreads();
  }

  // ---- P5/P6: sigma frag exchange + PV + store, two col-halves over kwL ----
  const int kb0 = wave >> 1, hi = wave & 1;
  #pragma unroll
  for (int half = 0; half < 2; ++half) {
    #pragma unroll
    for (int ntl = 0; ntl < 8; ++ntl) {
      uint2 o;
      const f32x4 v = acc2[half*8 + ntl];
      o.x = (u32)f2bf(v[0]) | ((u32)f2bf(v[1]) << 16);
      o.y = (u32)f2bf(v[2]) | ((u32)f2bf(v[3]) << 16);
      *(uint2*)(fragH + (((ntl*3 + kb0)*64 + lane) << 4) + hi*8) = o;
    }
    __syncthreads();   // frag half ready
    #pragma unroll
    for (int ntl = 0; ntl < 8; ++ntl) {
      f32x4 oa = (f32x4)0.f;
      #pragma unroll
      for (int kb = 0; kb < 3; ++kb) {
        const short8 ef = *(const short8*)(fragH + (((ntl*3 + kb)*64 + lane) << 4));
        oa = __builtin_amdgcn_mfma_f32_16x16x32_bf16(af[kb], ef, oa, 0, 0, 0);
      }
      const int c = c15 + 16*(half*8 + ntl);
      const float bz = bvoL[c];
      #pragma unroll
      for (int r = 0; r < 4; ++r) {
        const int qi = 16*wave + 4*g + r;
        out[((size_t)((b*96 + qi)*1024 + n))*256 + c] = oa[r] + bz;
      }
    }
    if (half == 0) __syncthreads();   // PV-A reads done before fragB writes
  }
}

// ---------------------------------------------------------------------------
extern "C" void kernel_launch(void* const* d_in, const int* in_sizes, int n_in,
                              void* d_out, int out_size, void* d_ws, size_t ws_size,
                              hipStream_t stream) {
  const float* enc     = (const float*)d_in[0];
  const float* ste_enc = (const float*)d_in[1];
  const float* ste_dec = (const float*)d_in[2];
  const float* Wq = (const float*)d_in[3];
  const float* bq = (const float*)d_in[4];
  const float* Wk = (const float*)d_in[5];
  const float* Wv = (const float*)d_in[7];
  const float* bv = (const float*)d_in[8];
  const float* Wo = (const float*)d_in[9];
  const float* bo = (const float*)d_in[10];
  float* out = (float*)d_out;

  u16*   WkqF = (u16*)d_ws;                               // 36864 B
  u16*   WvoF = (u16*)((char*)d_ws + 36864);              // 131072 B -> 167936
  float* bvo  = (float*)((char*)d_ws + 167936);           // 1024 B

  k_setup<<<dim3(256), dim3(256), 0, stream>>>(Wq, Wk, Wv, Wo, bq, bv, bo,
                                               WkqF, WvoF, bvo);
  k_attn<<<dim3(1024, 8), dim3(NTHR), LDS_TOTAL, stream>>>(
      ste_dec, ste_enc, enc, WkqF, WvoF, bvo, out);
}

// Round 10
// 643.607 us; speedup vs baseline: 1.2488x; 1.2488x over previous
//
#include <hip/hip_runtime.h>
#include <stdint.h>

typedef unsigned short u16;
typedef unsigned int u32;
typedef __attribute__((ext_vector_type(8))) short short8;   // 8 bf16 (4 VGPR)
typedef __attribute__((ext_vector_type(4))) float f32x4;

#define NTHR 384
#define K2E16 0.09016844005556021f   /* log2(e)/16 : 1/sqrt(256) folded into exp2 */

// LDS map (60288 B total; 2 blocks/CU = 120576 <= 160K pool):
//   wvoL  [0, 32768)  : Wvo per-kt 16KB chunks, double-buffered; later fragB (24576)
//   kwL   [32768, 58880): KW bf16 [96][272B] (26112); later fragA (24576)
//   biasL f32[96] @58880, bvoL f32[256] @59264
#define KW_OFF    32768
#define KW_STRIDE 272
#define BIAS_OFF  58880
#define BVO_OFF   59264
#define LDS_TOTAL 60288

static __device__ __forceinline__ u16 f2bf(float f) {
  union { float f; u32 u; } v; v.f = f;
  u32 r = v.u + 0x7FFFu + ((v.u >> 16) & 1u);   // RNE
  return (u16)(r >> 16);
}

// ---------------------------------------------------------------------------
// K0: weight prep.
//  - WkqE[de][c]: c<128 -> sum_h Wk[de][h]*Wq[c][h]; c==128 -> Wk[de]·bq;
//                 129..143 -> 0. bf16 MFMA B-frags (K=128, 9 col-tiles).
//    (bk-dependent score terms are constant over p -> cancel in softmax.)
//  - WvoF = bf16 B-frags of Wv@Wo, frag index (kt*16+nt): each kt's 16 nt
//    are a contiguous 16KB chunk (LDS-stageable per-kt).
//  - bvo = bv@Wo + bo (f32).
// ---------------------------------------------------------------------------
__global__ __launch_bounds__(256) void k_setup(
    const float* __restrict__ Wq, const float* __restrict__ Wk,
    const float* __restrict__ Wv, const float* __restrict__ Wo,
    const float* __restrict__ bq,
    const float* __restrict__ bv, const float* __restrict__ bo,
    u16* __restrict__ WkqF, u16* __restrict__ WvoF, float* __restrict__ bvo) {
  const int ci = blockIdx.x;   // k-row
  const int co = threadIdx.x;  // col
  float acc = 0.f;
  for (int h = 0; h < 256; ++h) acc += Wv[ci*256 + h] * Wo[h*256 + co];
  const int lanepart = ((ci >> 3) & 3)*16 + (co & 15), e = ci & 7;
  const int idxv = (((ci >> 5)*16 + (co >> 4))*64 + lanepart)*8 + e;
  WvoF[idxv] = f2bf(acc);
  if (ci < 128 && co < 144) {
    float a = 0.f;
    if (co < 128)       { for (int h = 0; h < 256; ++h) a += Wk[ci*256 + h] * Wq[co*256 + h]; }
    else if (co == 128) { for (int h = 0; h < 256; ++h) a += Wk[ci*256 + h] * bq[h]; }
    const int idx = (((ci >> 5)*9 + (co >> 4))*64 + lanepart)*8 + e;
    WkqF[idx] = f2bf(a);
  }
  if (ci == 0) {
    float a2 = 0.f;
    for (int h = 0; h < 256; ++h) a2 += bv[h] * Wo[h*256 + co];
    bvo[co] = a2 + bo[co];
  }
}

// ---------------------------------------------------------------------------
// K2 fused, grid (1024, 8), 6 waves, 60288B LDS, target 2 blocks/CU.
// M-partition: wave w owns rows [16w,16w+16) of every per-(b,n) matrix.
//   P0: issue sd/se reg loads + Wvo chunk0 loads; biases
//   P1: KW = bf16(senc_rows)@WkqE -> kwL (B-frags direct global, L2-hot);
//       col128 -> biasL; chunk0 -> wvoL.buf0
//   (preload enc ring slots 0..3 — fly under P2)
//   P2: scoresT = KW@sdecT + bias; softmax; af pack
//   P2b: 8x per-kt: {prefetch Wvo chunk kt+1; consume enc ring slot kt&3;
//        reload slot with row kt+4; 16 MFMA from buf[kt&1]; commit chunk;
//        barrier}   — enc held in a 4-slot ring (32 regs, not 64)
//   P5: acc2 -> sigma B-frags, fragA over kwL + fragB over wvoL, one sync
//   P6: out = attn@enc2 + bvo (16 col-tiles), f32 stores
// ---------------------------------------------------------------------------
__global__ __launch_bounds__(NTHR, 3) void k_attn(
    const float* __restrict__ sdec, const float* __restrict__ senc,
    const float* __restrict__ enc,
    const u16* __restrict__ WkqF, const u16* __restrict__ WvoF,
    const float* __restrict__ bvo, float* __restrict__ out) {
  extern __shared__ char smem[];
  char* wvoL   = smem;
  char* kwL    = smem + KW_OFF;
  char* fragA  = smem + KW_OFF;    // 24576 over kwL (P5+)
  char* fragB  = smem;             // 24576 over wvoL (P5+)
  float* biasL = (float*)(smem + BIAS_OFF);
  float* bvoL  = (float*)(smem + BVO_OFF);

  const int n = blockIdx.x, b = blockIdx.y;
  const int tid = threadIdx.x, wave = tid >> 6, lane = tid & 63;
  const int g = lane >> 4, c15 = lane & 15;
  const int prow = 16*wave + c15;      // this wave's A-fragment row

  // ---- P0: issue sdec/senc reg loads + Wvo chunk0 loads ----
  const float* sdp = sdec + ((size_t)((b*96 + prow)*1024 + n))*128 + 8*g;
  const float* sep = senc + ((size_t)((b*96 + prow)*1024 + n))*128 + 8*g;
  float4 sdv[4][2], sev[4][2];
  #pragma unroll
  for (int kt = 0; kt < 4; ++kt) {
    sev[kt][0] = *(const float4*)(sep + 32*kt);
    sev[kt][1] = *(const float4*)(sep + 32*kt + 4);
    sdv[kt][0] = *(const float4*)(sdp + 32*kt);
    sdv[kt][1] = *(const float4*)(sdp + 32*kt + 4);
  }
  const f32x4* wv = (const f32x4*)WvoF;   // chunk kt = wv + kt*1024 (16KB)
  f32x4 c0[3];
  #pragma unroll
  for (int i = 0; i < 3; ++i) {
    const int idx = tid + 384*i;
    if (idx < 1024) c0[i] = wv[idx];
  }
  if (tid < 256) bvoL[tid] = bvo[tid];

  short8 sef[4], sdf[4];
  #pragma unroll
  for (int kt = 0; kt < 4; ++kt) {
    union { u32 u[4]; short8 v; } cv;
    cv.u[0] = (u32)f2bf(sev[kt][0].x) | ((u32)f2bf(sev[kt][0].y) << 16);
    cv.u[1] = (u32)f2bf(sev[kt][0].z) | ((u32)f2bf(sev[kt][0].w) << 16);
    cv.u[2] = (u32)f2bf(sev[kt][1].x) | ((u32)f2bf(sev[kt][1].y) << 16);
    cv.u[3] = (u32)f2bf(sev[kt][1].z) | ((u32)f2bf(sev[kt][1].w) << 16);
    sef[kt] = cv.v;
  }
  #pragma unroll
  for (int kt = 0; kt < 4; ++kt) {
    union { u32 u[4]; short8 v; } cv;
    cv.u[0] = (u32)f2bf(sdv[kt][0].x) | ((u32)f2bf(sdv[kt][0].y) << 16);
    cv.u[1] = (u32)f2bf(sdv[kt][0].z) | ((u32)f2bf(sdv[kt][0].w) << 16);
    cv.u[2] = (u32)f2bf(sdv[kt][1].x) | ((u32)f2bf(sdv[kt][1].y) << 16);
    cv.u[3] = (u32)f2bf(sdv[kt][1].z) | ((u32)f2bf(sdv[kt][1].w) << 16);
    sdf[kt] = cv.v;
  }

  // ---- P1: KW rows [16w,16w+16) x 144 = senc_rows @ WkqE (B direct global) ----
  {
    f32x4 acc[9];
    #pragma unroll
    for (int nt = 0; nt < 9; ++nt) acc[nt] = (f32x4)0.f;
    #pragma unroll
    for (int kt = 0; kt < 4; ++kt) {
      #pragma unroll
      for (int nt = 0; nt < 9; ++nt) {
        const short8 bf = *(const short8*)(WkqF + (size_t)((kt*9 + nt)*64 + lane)*8);
        acc[nt] = __builtin_amdgcn_mfma_f32_16x16x32_bf16(sef[kt], bf, acc[nt], 0, 0, 0);
      }
    }
    #pragma unroll
    for (int nt = 0; nt < 8; ++nt) {
      #pragma unroll
      for (int r = 0; r < 4; ++r)
        *(u16*)(kwL + (16*wave + 4*g + r)*KW_STRIDE + 2*(c15 + 16*nt)) = f2bf(acc[nt][r]);
    }
    if (c15 == 0) {
      #pragma unroll
      for (int r = 0; r < 4; ++r) biasL[16*wave + 4*g + r] = acc[8][r];
    }
  }
  // commit Wvo chunk0 -> buf0
  {
    f32x4* b0 = (f32x4*)wvoL;
    #pragma unroll
    for (int i = 0; i < 3; ++i) {
      const int idx = tid + 384*i;
      if (idx < 1024) b0[idx] = c0[i];
    }
  }
  __syncthreads();   // bar1: kwL + biasL + chunk0 ready

  // ---- preload enc ring slots 0..3 (32 regs; land during P2) ----
  const float* ep = enc + ((size_t)((b*96 + prow)*1024 + n))*256 + 8*g;
  float4 evr[4][2];
  #pragma unroll
  for (int kt = 0; kt < 4; ++kt) {
    evr[kt][0] = *(const float4*)(ep + 32*kt);
    evr[kt][1] = *(const float4*)(ep + 32*kt + 4);
  }

  // ---- P2: scoresT = KW[:,0:128] @ sdecT + bias; softmax; af pack ----
  f32x4 sac[6];
  #pragma unroll
  for (int pt = 0; pt < 6; ++pt) sac[pt] = (f32x4)0.f;
  #pragma unroll
  for (int kt = 0; kt < 4; ++kt) {
    #pragma unroll
    for (int pt = 0; pt < 6; ++pt) {
      const short8 kf = *(const short8*)(kwL + (16*pt + c15)*KW_STRIDE + 16*g + 64*kt);
      sac[pt] = __builtin_amdgcn_mfma_f32_16x16x32_bf16(kf, sdf[kt], sac[pt], 0, 0, 0);
    }
  }
  #pragma unroll
  for (int pt = 0; pt < 6; ++pt)
    #pragma unroll
    for (int r = 0; r < 4; ++r)
      sac[pt][r] += biasL[16*pt + 4*g + r];

  float m = sac[0][0];
  #pragma unroll
  for (int pt = 0; pt < 6; ++pt)
    #pragma unroll
    for (int r = 0; r < 4; ++r) m = fmaxf(m, sac[pt][r]);
  m = fmaxf(m, __shfl_xor(m, 16));
  m = fmaxf(m, __shfl_xor(m, 32));
  float s = 0.f;
  #pragma unroll
  for (int pt = 0; pt < 6; ++pt)
    #pragma unroll
    for (int r = 0; r < 4; ++r) {
      const float e = exp2f((sac[pt][r] - m) * K2E16);
      sac[pt][r] = e; s += e;
    }
  s += __shfl_xor(s, 16);
  s += __shfl_xor(s, 32);
  const float rs = 1.f / s;

  short8 af[3];
  #pragma unroll
  for (int kb = 0; kb < 3; ++kb) {
    union { u32 u[4]; short8 v; } cv;
    cv.u[0] = (u32)f2bf(sac[2*kb][0]*rs)   | ((u32)f2bf(sac[2*kb][1]*rs)   << 16);
    cv.u[1] = (u32)f2bf(sac[2*kb][2]*rs)   | ((u32)f2bf(sac[2*kb][3]*rs)   << 16);
    cv.u[2] = (u32)f2bf(sac[2*kb+1][0]*rs) | ((u32)f2bf(sac[2*kb+1][1]*rs) << 16);
    cv.u[3] = (u32)f2bf(sac[2*kb+1][2]*rs) | ((u32)f2bf(sac[2*kb+1][3]*rs) << 16);
    af[kb] = cv.v;
  }

  // ---- P2b: enc2 = enc_rows @ Wvo; 8 x 16KB chunks dbuf; enc via 4-ring ----
  f32x4 acc2[16];
  #pragma unroll
  for (int nt = 0; nt < 16; ++nt) acc2[nt] = (f32x4)0.f;
  #pragma unroll
  for (int kt = 0; kt < 8; ++kt) {
    // prefetch next Wvo chunk to regs (flies under this kt's MFMAs)
    f32x4 nx[3];
    if (kt < 7) {
      const f32x4* src = wv + (kt + 1)*1024;
      #pragma unroll
      for (int i = 0; i < 3; ++i) {
        const int idx = tid + 384*i;
        if (idx < 1024) nx[i] = src[idx];
      }
    }
    // consume enc ring slot kt&3; then reload it with row-chunk kt+4
    union { u32 u[4]; short8 v; } cv;
    cv.u[0] = (u32)f2bf(evr[kt & 3][0].x) | ((u32)f2bf(evr[kt & 3][0].y) << 16);
    cv.u[1] = (u32)f2bf(evr[kt & 3][0].z) | ((u32)f2bf(evr[kt & 3][0].w) << 16);
    cv.u[2] = (u32)f2bf(evr[kt & 3][1].x) | ((u32)f2bf(evr[kt & 3][1].y) << 16);
    cv.u[3] = (u32)f2bf(evr[kt & 3][1].z) | ((u32)f2bf(evr[kt & 3][1].w) << 16);
    const short8 a = cv.v;
    if (kt < 4) {
      evr[kt & 3][0] = *(const float4*)(ep + 32*(kt + 4));
      evr[kt & 3][1] = *(const float4*)(ep + 32*(kt + 4) + 4);
    }
    const char* buf = wvoL + (kt & 1)*16384;
    #pragma unroll
    for (int nt = 0; nt < 16; ++nt) {
      const short8 bf = *(const short8*)(buf + ((nt*64 + lane) << 4));
      acc2[nt] = __builtin_amdgcn_mfma_f32_16x16x32_bf16(a, bf, acc2[nt], 0, 0, 0);
    }
    // commit next chunk to the other buffer (safe: its readers synced last iter)
    if (kt < 7) {
      f32x4* bw = (f32x4*)(wvoL + ((kt + 1) & 1)*16384);
      #pragma unroll
      for (int i = 0; i < 3; ++i) {
        const int idx = tid + 384*i;
        if (idx < 1024) bw[idx] = nx[i];
      }
    }
    __syncthreads();
  }

  // ---- P5: acc2 -> sigma B-frags; fragA (nt 0..7) + fragB (nt 8..15) ----
  const int kb0 = wave >> 1, hi = wave & 1;
  #pragma unroll
  for (int ntl = 0; ntl < 8; ++ntl) {
    uint2 oA, oB;
    const f32x4 vA = acc2[ntl], vB = acc2[8 + ntl];
    oA.x = (u32)f2bf(vA[0]) | ((u32)f2bf(vA[1]) << 16);
    oA.y = (u32)f2bf(vA[2]) | ((u32)f2bf(vA[3]) << 16);
    oB.x = (u32)f2bf(vB[0]) | ((u32)f2bf(vB[1]) << 16);
    oB.y = (u32)f2bf(vB[2]) | ((u32)f2bf(vB[3]) << 16);
    *(uint2*)(fragA + (((ntl*3 + kb0)*64 + lane) << 4) + hi*8) = oA;
    *(uint2*)(fragB + (((ntl*3 + kb0)*64 + lane) << 4) + hi*8) = oB;
  }
  __syncthreads();   // frags ready

  // ---- P6: out = attn @ enc2 + bvo; f32 store ----
  #pragma unroll
  for (int nt = 0; nt < 16; ++nt) {
    const char* fb = (nt < 8) ? fragA : fragB;
    const int ntl = nt & 7;
    f32x4 oa = (f32x4)0.f;
    #pragma unroll
    for (int kb = 0; kb < 3; ++kb) {
      const short8 ef = *(const short8*)(fb + (((ntl*3 + kb)*64 + lane) << 4));
      oa = __builtin_amdgcn_mfma_f32_16x16x32_bf16(af[kb], ef, oa, 0, 0, 0);
    }
    const int c = c15 + 16*nt;
    const float bz = bvoL[c];
    #pragma unroll
    for (int r = 0; r < 4; ++r) {
      const int qi = 16*wave + 4*g + r;
      out[((size_t)((b*96 + qi)*1024 + n))*256 + c] = oa[r] + bz;
    }
  }
}

// ---------------------------------------------------------------------------
extern "C" void kernel_launch(void* const* d_in, const int* in_sizes, int n_in,
                              void* d_out, int out_size, void* d_ws, size_t ws_size,
                              hipStream_t stream) {
  const float* enc     = (const float*)d_in[0];
  const float* ste_enc = (const float*)d_in[1];
  const float* ste_dec = (const float*)d_in[2];
  const float* Wq = (const float*)d_in[3];
  const float* bq = (const float*)d_in[4];
  const float* Wk = (const float*)d_in[5];
  const float* Wv = (const float*)d_in[7];
  const float* bv = (const float*)d_in[8];
  const float* Wo = (const float*)d_in[9];
  const float* bo = (const float*)d_in[10];
  float* out = (float*)d_out;

  u16*   WkqF = (u16*)d_ws;                               // 36864 B
  u16*   WvoF = (u16*)((char*)d_ws + 36864);              // 131072 B -> 167936
  float* bvo  = (float*)((char*)d_ws + 167936);           // 1024 B

  k_setup<<<dim3(256), dim3(256), 0, stream>>>(Wq, Wk, Wv, Wo, bq, bv, bo,
                                               WkqF, WvoF, bvo);
  k_attn<<<dim3(1024, 8), dim3(NTHR), LDS_TOTAL, stream>>>(
      ste_dec, ste_enc, enc, WkqF, WvoF, bvo, out);
}

// Round 11
// 608.882 us; speedup vs baseline: 1.3201x; 1.0570x over previous
//
#include <hip/hip_runtime.h>
#include <stdint.h>

typedef unsigned short u16;
typedef unsigned int u32;
typedef __attribute__((ext_vector_type(8))) short short8;   // 8 bf16 (4 VGPR)
typedef __attribute__((ext_vector_type(4))) float f32x4;

#define NTHR 384
#define K2E16 0.09016844005556021f   /* log2(e)/16 : 1/sqrt(256) folded into exp2 */

// LDS map (60288 B total):
//   wvoL  [0, 32768)  : Wkq compact (32KB, P0..P1) -> Wvo 16KB dbuf chunks (P2b)
//                       -> fragB (24576, P5..P6)
//   kwL   [32768, 58880): KW bf16 [96][272B] (26112, P1..P2) -> fragA (24576)
//   biasL f32[96] @58880, bvoL f32[256] @59264
#define KW_OFF    32768
#define KW_STRIDE 272
#define BIAS_OFF  58880
#define BVO_OFF   59264
#define LDS_TOTAL 60288

static __device__ __forceinline__ u16 f2bf(float f) {
  union { float f; u32 u; } v; v.f = f;
  u32 r = v.u + 0x7FFFu + ((v.u >> 16) & 1u);   // RNE
  return (u16)(r >> 16);
}

// ---------------------------------------------------------------------------
// K0: weight prep.  (identical to round-10 verified version)
//  - WkqE[de][c]: c<128 -> sum_h Wk[de][h]*Wq[c][h]; c==128 -> Wk[de]·bq;
//                 129..143 -> 0. bf16 MFMA B-frags (K=128, 9 col-tiles).
//  - WvoF = bf16 B-frags of Wv@Wo, frag (kt*16+nt): each kt = 16KB chunk.
//  - bvo = bv@Wo + bo (f32).
// ---------------------------------------------------------------------------
__global__ __launch_bounds__(256) void k_setup(
    const float* __restrict__ Wq, const float* __restrict__ Wk,
    const float* __restrict__ Wv, const float* __restrict__ Wo,
    const float* __restrict__ bq,
    const float* __restrict__ bv, const float* __restrict__ bo,
    u16* __restrict__ WkqF, u16* __restrict__ WvoF, float* __restrict__ bvo) {
  const int ci = blockIdx.x;   // k-row
  const int co = threadIdx.x;  // col
  float acc = 0.f;
  for (int h = 0; h < 256; ++h) acc += Wv[ci*256 + h] * Wo[h*256 + co];
  const int lanepart = ((ci >> 3) & 3)*16 + (co & 15), e = ci & 7;
  const int idxv = (((ci >> 5)*16 + (co >> 4))*64 + lanepart)*8 + e;
  WvoF[idxv] = f2bf(acc);
  if (ci < 128 && co < 144) {
    float a = 0.f;
    if (co < 128)       { for (int h = 0; h < 256; ++h) a += Wk[ci*256 + h] * Wq[co*256 + h]; }
    else if (co == 128) { for (int h = 0; h < 256; ++h) a += Wk[ci*256 + h] * bq[h]; }
    const int idx = (((ci >> 5)*9 + (co >> 4))*64 + lanepart)*8 + e;
    WkqF[idx] = f2bf(a);
  }
  if (ci == 0) {
    float a2 = 0.f;
    for (int h = 0; h < 256; ++h) a2 += bv[h] * Wo[h*256 + co];
    bvo[co] = a2 + bo[co];
  }
}

// ---------------------------------------------------------------------------
// K2 fused, grid (1024, 8), 6 waves, 60288B LDS, 1 block/CU (by design).
// Latency-chain minimized: all weight tables flow through LDS with loads
// issued >=1 phase ahead of use.
//   P0: issue Wkq-stage loads (32KB->wvoL), sd/se loads, Wvo chunk0, bvo
//   P1: KW = senc_rows@WkqE -> kwL; B-frags nt0-7 from LDS, nt8 direct
//   bar1 -> commit chunk0; issue chunk1; preload enc ring; P2 scores+softmax
//   bar2 -> P2b: 8 iters, Wvo reg-prefetch 2 chunks deep, LDS dbuf
//   P5: acc2 -> sigma B-frags (fragA over kwL, fragB over wvoL), one sync
//   P6: out = attn@enc2 + bvo
// ---------------------------------------------------------------------------
__global__ __launch_bounds__(NTHR, 2) void k_attn(
    const float* __restrict__ sdec, const float* __restrict__ senc,
    const float* __restrict__ enc,
    const u16* __restrict__ WkqF, const u16* __restrict__ WvoF,
    const float* __restrict__ bvo, float* __restrict__ out) {
  extern __shared__ char smem[];
  char* wvoL   = smem;             // Wkq stage, then Wvo dbuf, then fragB
  char* kwL    = smem + KW_OFF;
  char* fragA  = smem + KW_OFF;
  char* fragB  = smem;
  float* biasL = (float*)(smem + BIAS_OFF);
  float* bvoL  = (float*)(smem + BVO_OFF);

  const int n = blockIdx.x, b = blockIdx.y;
  const int tid = threadIdx.x, wave = tid >> 6, lane = tid & 63;
  const int g = lane >> 4, c15 = lane & 15;
  const int prow = 16*wave + c15;      // this wave's A-fragment row

  // ---- P0: issue Wkq stage loads FIRST (oldest -> earliest waitable) ----
  f32x4 wkq[6];
  #pragma unroll
  for (int i = 0; i < 6; ++i) {
    const int idx = tid + 384*i;
    if (idx < 2048) {
      const int f = idx >> 6, l = idx & 63;          // frag 0..31, lane-slot
      wkq[i] = ((const f32x4*)WkqF)[((f >> 3)*9 + (f & 7))*64 + l];
    }
  }
  // sd/se fragment loads (wave-own rows)
  const float* sdp = sdec + ((size_t)((b*96 + prow)*1024 + n))*128 + 8*g;
  const float* sep = senc + ((size_t)((b*96 + prow)*1024 + n))*128 + 8*g;
  float4 sdv[4][2], sev[4][2];
  #pragma unroll
  for (int kt = 0; kt < 4; ++kt) {
    sev[kt][0] = *(const float4*)(sep + 32*kt);
    sev[kt][1] = *(const float4*)(sep + 32*kt + 4);
    sdv[kt][0] = *(const float4*)(sdp + 32*kt);
    sdv[kt][1] = *(const float4*)(sdp + 32*kt + 4);
  }
  const f32x4* wv = (const f32x4*)WvoF;   // chunk kt = wv + kt*1024 (16KB)
  f32x4 c0[3];
  #pragma unroll
  for (int i = 0; i < 3; ++i) {
    const int idx = tid + 384*i;
    if (idx < 1024) c0[i] = wv[idx];
  }
  if (tid < 256) bvoL[tid] = bvo[tid];

  // commit Wkq -> wvoL (waits only its own 6 loads; sd/se/c0 keep flying)
  {
    f32x4* d = (f32x4*)wvoL;
    #pragma unroll
    for (int i = 0; i < 6; ++i) {
      const int idx = tid + 384*i;
      if (idx < 2048) d[idx] = wkq[i];
    }
  }
  __syncthreads();   // bar0: Wkq staged

  short8 sef[4], sdf[4];
  #pragma unroll
  for (int kt = 0; kt < 4; ++kt) {
    union { u32 u[4]; short8 v; } cv;
    cv.u[0] = (u32)f2bf(sev[kt][0].x) | ((u32)f2bf(sev[kt][0].y) << 16);
    cv.u[1] = (u32)f2bf(sev[kt][0].z) | ((u32)f2bf(sev[kt][0].w) << 16);
    cv.u[2] = (u32)f2bf(sev[kt][1].x) | ((u32)f2bf(sev[kt][1].y) << 16);
    cv.u[3] = (u32)f2bf(sev[kt][1].z) | ((u32)f2bf(sev[kt][1].w) << 16);
    sef[kt] = cv.v;
  }
  #pragma unroll
  for (int kt = 0; kt < 4; ++kt) {
    union { u32 u[4]; short8 v; } cv;
    cv.u[0] = (u32)f2bf(sdv[kt][0].x) | ((u32)f2bf(sdv[kt][0].y) << 16);
    cv.u[1] = (u32)f2bf(sdv[kt][0].z) | ((u32)f2bf(sdv[kt][0].w) << 16);
    cv.u[2] = (u32)f2bf(sdv[kt][1].x) | ((u32)f2bf(sdv[kt][1].y) << 16);
    cv.u[3] = (u32)f2bf(sdv[kt][1].z) | ((u32)f2bf(sdv[kt][1].w) << 16);
    sdf[kt] = cv.v;
  }

  // ---- P1: KW rows [16w,16w+16) x 144 = senc_rows @ WkqE ----
  {
    f32x4 acc[9];
    #pragma unroll
    for (int nt = 0; nt < 9; ++nt) acc[nt] = (f32x4)0.f;
    #pragma unroll
    for (int kt = 0; kt < 4; ++kt) {
      #pragma unroll
      for (int nt = 0; nt < 8; ++nt) {
        const short8 bf = *(const short8*)(wvoL + ((kt*8 + nt)*64 + lane)*16);
        acc[nt] = __builtin_amdgcn_mfma_f32_16x16x32_bf16(sef[kt], bf, acc[nt], 0, 0, 0);
      }
      const short8 bf8 = *(const short8*)(WkqF + (size_t)((kt*9 + 8)*64 + lane)*8);
      acc[8] = __builtin_amdgcn_mfma_f32_16x16x32_bf16(sef[kt], bf8, acc[8], 0, 0, 0);
    }
    #pragma unroll
    for (int nt = 0; nt < 8; ++nt) {
      #pragma unroll
      for (int r = 0; r < 4; ++r)
        *(u16*)(kwL + (16*wave + 4*g + r)*KW_STRIDE + 2*(c15 + 16*nt)) = f2bf(acc[nt][r]);
    }
    if (c15 == 0) {
      #pragma unroll
      for (int r = 0; r < 4; ++r) biasL[16*wave + 4*g + r] = acc[8][r];
    }
  }
  __syncthreads();   // bar1: kwL + biasL ready; wvoL (Wkq) reads done

  // ---- commit chunk0 -> buf0; issue chunk1 -> pf0 (lands during P2) ----
  {
    f32x4* b0 = (f32x4*)wvoL;
    #pragma unroll
    for (int i = 0; i < 3; ++i) {
      const int idx = tid + 384*i;
      if (idx < 1024) b0[idx] = c0[i];
    }
  }
  f32x4 pf0[3], pf1[3];
  #pragma unroll
  for (int i = 0; i < 3; ++i) {
    const int idx = tid + 384*i;
    if (idx < 1024) pf0[i] = wv[1024 + idx];
  }
  // preload enc ring slots 0..3 (land during P2)
  const float* ep = enc + ((size_t)((b*96 + prow)*1024 + n))*256 + 8*g;
  float4 evr[4][2];
  #pragma unroll
  for (int kt = 0; kt < 4; ++kt) {
    evr[kt][0] = *(const float4*)(ep + 32*kt);
    evr[kt][1] = *(const float4*)(ep + 32*kt + 4);
  }

  // ---- P2: scoresT = KW[:,0:128] @ sdecT + bias; softmax; af pack ----
  f32x4 sac[6];
  #pragma unroll
  for (int pt = 0; pt < 6; ++pt) sac[pt] = (f32x4)0.f;
  #pragma unroll
  for (int kt = 0; kt < 4; ++kt) {
    #pragma unroll
    for (int pt = 0; pt < 6; ++pt) {
      const short8 kf = *(const short8*)(kwL + (16*pt + c15)*KW_STRIDE + 16*g + 64*kt);
      sac[pt] = __builtin_amdgcn_mfma_f32_16x16x32_bf16(kf, sdf[kt], sac[pt], 0, 0, 0);
    }
  }
  #pragma unroll
  for (int pt = 0; pt < 6; ++pt)
    #pragma unroll
    for (int r = 0; r < 4; ++r)
      sac[pt][r] += biasL[16*pt + 4*g + r];

  float m = sac[0][0];
  #pragma unroll
  for (int pt = 0; pt < 6; ++pt)
    #pragma unroll
    for (int r = 0; r < 4; ++r) m = fmaxf(m, sac[pt][r]);
  m = fmaxf(m, __shfl_xor(m, 16));
  m = fmaxf(m, __shfl_xor(m, 32));
  float s = 0.f;
  #pragma unroll
  for (int pt = 0; pt < 6; ++pt)
    #pragma unroll
    for (int r = 0; r < 4; ++r) {
      const float e = exp2f((sac[pt][r] - m) * K2E16);
      sac[pt][r] = e; s += e;
    }
  s += __shfl_xor(s, 16);
  s += __shfl_xor(s, 32);
  const float rs = 1.f / s;

  short8 af[3];
  #pragma unroll
  for (int kb = 0; kb < 3; ++kb) {
    union { u32 u[4]; short8 v; } cv;
    cv.u[0] = (u32)f2bf(sac[2*kb][0]*rs)   | ((u32)f2bf(sac[2*kb][1]*rs)   << 16);
    cv.u[1] = (u32)f2bf(sac[2*kb][2]*rs)   | ((u32)f2bf(sac[2*kb][3]*rs)   << 16);
    cv.u[2] = (u32)f2bf(sac[2*kb+1][0]*rs) | ((u32)f2bf(sac[2*kb+1][1]*rs) << 16);
    cv.u[3] = (u32)f2bf(sac[2*kb+1][2]*rs) | ((u32)f2bf(sac[2*kb+1][3]*rs) << 16);
    af[kb] = cv.v;
  }
  __syncthreads();   // bar2: chunk0 visible to all; kwL reads (P2) done

  // ---- P2b: enc2 = enc_rows @ Wvo; 8 chunks, reg-prefetch 2 deep ----
  // chunk c: issued iter c-2 into pf[(c+1)&1], committed iter c-1, read iter c
  f32x4 acc2[16];
  #pragma unroll
  for (int nt = 0; nt < 16; ++nt) acc2[nt] = (f32x4)0.f;
  #pragma unroll
  for (int kt = 0; kt < 8; ++kt) {
    // issue chunk kt+2 into pf[(kt+1)&1] (overwrites dead chunk kt regs)
    if (kt < 6) {
      const f32x4* src = wv + (kt + 2)*1024;
      if (((kt + 1) & 1) == 0) {
        #pragma unroll
        for (int i = 0; i < 3; ++i) { const int idx = tid + 384*i; if (idx < 1024) pf0[i] = src[idx]; }
      } else {
        #pragma unroll
        for (int i = 0; i < 3; ++i) { const int idx = tid + 384*i; if (idx < 1024) pf1[i] = src[idx]; }
      }
    }
    // consume enc ring slot kt&3; reload it with row-chunk kt+4
    union { u32 u[4]; short8 v; } cv;
    cv.u[0] = (u32)f2bf(evr[kt & 3][0].x) | ((u32)f2bf(evr[kt & 3][0].y) << 16);
    cv.u[1] = (u32)f2bf(evr[kt & 3][0].z) | ((u32)f2bf(evr[kt & 3][0].w) << 16);
    cv.u[2] = (u32)f2bf(evr[kt & 3][1].x) | ((u32)f2bf(evr[kt & 3][1].y) << 16);
    cv.u[3] = (u32)f2bf(evr[kt & 3][1].z) | ((u32)f2bf(evr[kt & 3][1].w) << 16);
    const short8 a = cv.v;
    if (kt < 4) {
      evr[kt & 3][0] = *(const float4*)(ep + 32*(kt + 4));
      evr[kt & 3][1] = *(const float4*)(ep + 32*(kt + 4) + 4);
    }
    const char* buf = wvoL + (kt & 1)*16384;
    #pragma unroll
    for (int nt = 0; nt < 16; ++nt) {
      const short8 bf = *(const short8*)(buf + ((nt*64 + lane) << 4));
      acc2[nt] = __builtin_amdgcn_mfma_f32_16x16x32_bf16(a, bf, acc2[nt], 0, 0, 0);
    }
    // commit chunk kt+1 (in pf[kt&1], issued iter kt-1) -> buf[(kt+1)&1]
    if (kt < 7) {
      f32x4* bw = (f32x4*)(wvoL + ((kt + 1) & 1)*16384);
      if ((kt & 1) == 0) {
        #pragma unroll
        for (int i = 0; i < 3; ++i) { const int idx = tid + 384*i; if (idx < 1024) bw[idx] = pf0[i]; }
      } else {
        #pragma unroll
        for (int i = 0; i < 3; ++i) { const int idx = tid + 384*i; if (idx < 1024) bw[idx] = pf1[i]; }
      }
    }
    __syncthreads();
  }

  // ---- P5: acc2 -> sigma B-frags; fragA (nt 0..7) + fragB (nt 8..15) ----
  const int kb0 = wave >> 1, hi = wave & 1;
  #pragma unroll
  for (int ntl = 0; ntl < 8; ++ntl) {
    uint2 oA, oB;
    const f32x4 vA = acc2[ntl], vB = acc2[8 + ntl];
    oA.x = (u32)f2bf(vA[0]) | ((u32)f2bf(vA[1]) << 16);
    oA.y = (u32)f2bf(vA[2]) | ((u32)f2bf(vA[3]) << 16);
    oB.x = (u32)f2bf(vB[0]) | ((u32)f2bf(vB[1]) << 16);
    oB.y = (u32)f2bf(vB[2]) | ((u32)f2bf(vB[3]) << 16);
    *(uint2*)(fragA + (((ntl*3 + kb0)*64 + lane) << 4) + hi*8) = oA;
    *(uint2*)(fragB + (((ntl*3 + kb0)*64 + lane) << 4) + hi*8) = oB;
  }
  __syncthreads();   // frags ready

  // ---- P6: out = attn @ enc2 + bvo; f32 store ----
  #pragma unroll
  for (int nt = 0; nt < 16; ++nt) {
    const char* fb = (nt < 8) ? fragA : fragB;
    const int ntl = nt & 7;
    f32x4 oa = (f32x4)0.f;
    #pragma unroll
    for (int kb = 0; kb < 3; ++kb) {
      const short8 ef = *(const short8*)(fb + (((ntl*3 + kb)*64 + lane) << 4));
      oa = __builtin_amdgcn_mfma_f32_16x16x32_bf16(af[kb], ef, oa, 0, 0, 0);
    }
    const int c = c15 + 16*nt;
    const float bz = bvoL[c];
    #pragma unroll
    for (int r = 0; r < 4; ++r) {
      const int qi = 16*wave + 4*g + r;
      out[((size_t)((b*96 + qi)*1024 + n))*256 + c] = oa[r] + bz;
    }
  }
}

// ---------------------------------------------------------------------------
extern "C" void kernel_launch(void* const* d_in, const int* in_sizes, int n_in,
                              void* d_out, int out_size, void* d_ws, size_t ws_size,
                              hipStream_t stream) {
  const float* enc     = (const float*)d_in[0];
  const float* ste_enc = (const float*)d_in[1];
  const float* ste_dec = (const float*)d_in[2];
  const float* Wq = (const float*)d_in[3];
  const float* bq = (const float*)d_in[4];
  const float* Wk = (const float*)d_in[5];
  const float* Wv = (const float*)d_in[7];
  const float* bv = (const float*)d_in[8];
  const float* Wo = (const float*)d_in[9];
  const float* bo = (const float*)d_in[10];
  float* out = (float*)d_out;

  u16*   WkqF = (u16*)d_ws;                               // 36864 B
  u16*   WvoF = (u16*)((char*)d_ws + 36864);              // 131072 B -> 167936
  float* bvo  = (float*)((char*)d_ws + 167936);           // 1024 B

  k_setup<<<dim3(256), dim3(256), 0, stream>>>(Wq, Wk, Wv, Wo, bq, bv, bo,
                                               WkqF, WvoF, bvo);
  k_attn<<<dim3(1024, 8), dim3(NTHR), LDS_TOTAL, stream>>>(
      ste_dec, ste_enc, enc, WkqF, WvoF, bvo, out);
}